// Round 10
// baseline (7919.000 us; speedup 1.0000x reference)
//
#include <hip/hip_runtime.h>
#include <hip/hip_bf16.h>
#include <hip/hip_fp8.h>

// ---------------- constants ----------------
#define LL   12
#define DD   1024
#define FF   4096
#define TTOK 128
#define VV   50257
#define NBLK 512
#define NTH  512
#define NGRP 12
#define GBLK 42                 // blocks per layer group (12*42=504, +8 head)
#define NHEAD (NBLK - NGRP * GBLK)
#define NSTEP (TTOK / 2 + NGRP) // 76 wavefront steps (2 tokens each)
#define WSC  256.0f             // fp8 encode scale
#define XSC  (1.0f / 256.0f)    // folded into x staging

// ---------------- coherent (cross-XCD) access helpers ----------------
__device__ __forceinline__ float cld(const float* p) {
    return __hip_atomic_load((float*)p, __ATOMIC_RELAXED, __HIP_MEMORY_SCOPE_AGENT);
}
__device__ __forceinline__ void cst(float* p, float v) {
    __hip_atomic_store(p, v, __ATOMIC_RELAXED, __HIP_MEMORY_SCOPE_AGENT);
}

// ---------------- small helpers ----------------
__device__ __host__ __forceinline__ unsigned short f2bf(float f) {
    union { float f; unsigned u; } x; x.f = f;
    unsigned r = x.u + 0x7fffu + ((x.u >> 16) & 1u);
    return (unsigned short)(r >> 16);
}

__device__ __forceinline__ unsigned pack_bf2(float a, float b) {
    return (unsigned)f2bf(a) | ((unsigned)f2bf(b) << 16);
}

__device__ __forceinline__ void ld8(const float* p, float* o) {
    float4 a = ((const float4*)p)[0], b = ((const float4*)p)[1];
    o[0]=a.x; o[1]=a.y; o[2]=a.z; o[3]=a.w; o[4]=b.x; o[5]=b.y; o[6]=b.z; o[7]=b.w;
}

__device__ __forceinline__ void bf8unpack(uint4 u, float* o) {
    union { unsigned u; float f; } t;
    t.u = u.x << 16;         o[0] = t.f;
    t.u = u.x & 0xffff0000u; o[1] = t.f;
    t.u = u.y << 16;         o[2] = t.f;
    t.u = u.y & 0xffff0000u; o[3] = t.f;
    t.u = u.z << 16;         o[4] = t.f;
    t.u = u.z & 0xffff0000u; o[5] = t.f;
    t.u = u.w << 16;         o[6] = t.f;
    t.u = u.w & 0xffff0000u; o[7] = t.f;
}

__device__ __forceinline__ void xld8(const unsigned short* x, int chunk, float* o) {
    uint4 u = *reinterpret_cast<const uint4*>(x + (chunk << 3));
    bf8unpack(u, o);
}
// resident 16-elem x segment for lane (seg 0 layout: elems 8l.. & 512+8l..)
__device__ __forceinline__ void xres(const unsigned short* xb, int lane, float* o) {
    xld8(xb, lane, o); xld8(xb, lane + 64, o + 8);
}

// ---------------- fp8 e4m3 decode/encode ----------------
typedef __attribute__((ext_vector_type(2))) float f32x2_t;

__device__ __forceinline__ void fp8x4(unsigned v, float* o) {
#if __has_builtin(__builtin_amdgcn_cvt_pk_f32_fp8)
    f32x2_t a = __builtin_amdgcn_cvt_pk_f32_fp8(v, false);
    f32x2_t b = __builtin_amdgcn_cvt_pk_f32_fp8(v, true);
    o[0] = a[0]; o[1] = a[1]; o[2] = b[0]; o[3] = b[1];
#else
    #pragma unroll
    for (int i = 0; i < 4; ++i) {
        __hip_fp8_e4m3 t; t.__x = (__hip_fp8_storage_t)((v >> (8 * i)) & 0xffu);
        o[i] = (float)t;
    }
#endif
}

__device__ __forceinline__ unsigned enc_fp8x4(float4 f) {
#if __has_builtin(__builtin_amdgcn_cvt_pk_fp8_f32)
    int d = 0;
    d = __builtin_amdgcn_cvt_pk_fp8_f32(f.x, f.y, d, false);
    d = __builtin_amdgcn_cvt_pk_fp8_f32(f.z, f.w, d, true);
    return (unsigned)d;
#else
    __hip_fp8_e4m3 a(f.x), b(f.y), c(f.z), e(f.w);
    return (unsigned)a.__x | ((unsigned)b.__x << 8) |
           ((unsigned)c.__x << 16) | ((unsigned)e.__x << 24);
#endif
}

__device__ __forceinline__ float dot16u(uint4 w, const float* x) {
    float wf[4], s;
    fp8x4(w.x, wf); s  = wf[0]*x[0] +wf[1]*x[1] +wf[2]*x[2] +wf[3]*x[3];
    fp8x4(w.y, wf); s += wf[0]*x[4] +wf[1]*x[5] +wf[2]*x[6] +wf[3]*x[7];
    fp8x4(w.z, wf); s += wf[0]*x[8] +wf[1]*x[9] +wf[2]*x[10]+wf[3]*x[11];
    fp8x4(w.w, wf); s += wf[0]*x[12]+wf[1]*x[13]+wf[2]*x[14]+wf[3]*x[15];
    return s;
}
__device__ __forceinline__ float dot16f(const float* w, const float* x) {
    float s = 0.f;
    #pragma unroll
    for (int i = 0; i < 16; ++i) s += w[i] * x[i];
    return s;
}

// generic 16-elem weight segment (F8 = packed uint4; f32 = 16 floats)
template<bool F8> struct WSeg;
template<> struct WSeg<true>  { uint4 v; };
template<> struct WSeg<false> { float f[16]; };

__device__ __forceinline__ void wseg_load(WSeg<true>& d, const void* w, long row,
                                          int segs, int m, int lane) {
    d.v = *(const uint4*)((const unsigned char*)w + (((row * segs + m) << 10) + (lane << 4)));
}
__device__ __forceinline__ void wseg_load(WSeg<false>& d, const void* w, long row,
                                          int segs, int m, int lane) {
    const float* p = (const float*)w + ((long)(row * segs + m) << 10);
    ld8(p + (lane << 3), d.f);
    ld8(p + 512 + (lane << 3), d.f + 8);
}
__device__ __forceinline__ float wseg_dot(const WSeg<true>& d, const float* x) { return dot16u(d.v, x); }
__device__ __forceinline__ float wseg_dot(const WSeg<false>& d, const float* x) { return dot16f(d.f, x); }

__device__ __forceinline__ float wred(float s) {
    #pragma unroll
    for (int o = 32; o; o >>= 1) s += __shfl_xor(s, o, 64);
    return s;
}

// block stats over x[1024] (512 threads): mean + rstd
__device__ __forceinline__ void bstats(const float* x, float* red, float& m, float& rs) {
    int tid = threadIdx.x;
    float a = x[tid], b = x[tid + 512];
    float s0 = a + b, s1 = a*a + b*b;
    #pragma unroll
    for (int o = 32; o; o >>= 1) { s0 += __shfl_xor(s0, o, 64); s1 += __shfl_xor(s1, o, 64); }
    if ((tid & 63) == 0) { red[(tid >> 6) * 2] = s0; red[(tid >> 6) * 2 + 1] = s1; }
    __syncthreads();
    float ms = 0.f, qs = 0.f;
    #pragma unroll
    for (int w = 0; w < 8; ++w) { ms += red[w * 2]; qs += red[w * 2 + 1]; }
    ms *= (1.f / 1024.f); qs *= (1.f / 1024.f);
    m = ms; rs = rsqrtf(qs - ms * ms + 1e-5f);
    __syncthreads();
}

// ---------------- group barrier (flat counter, sense-reversing) --------------
__device__ __forceinline__ void grpbar(unsigned* bar, int grp, unsigned n, unsigned& sen) {
    __syncthreads();
    if (threadIdx.x == 0) {
        unsigned s = sen ^ 1u;
        unsigned* cnt = &bar[grp * 64];
        unsigned* sns = &bar[grp * 64 + 32];
        unsigned prev = __hip_atomic_fetch_add(cnt, 1u, __ATOMIC_RELAXED, __HIP_MEMORY_SCOPE_AGENT);
        if (prev == n - 1u) {
            __hip_atomic_store(cnt, 0u, __ATOMIC_RELAXED, __HIP_MEMORY_SCOPE_AGENT);
            asm volatile("s_waitcnt vmcnt(0)" ::: "memory");
            __hip_atomic_store(sns, s, __ATOMIC_RELAXED, __HIP_MEMORY_SCOPE_AGENT);
        } else {
            while (__hip_atomic_load(sns, __ATOMIC_RELAXED, __HIP_MEMORY_SCOPE_AGENT) != s)
                __builtin_amdgcn_s_sleep(1);
        }
    }
    sen ^= 1u;
    __syncthreads();
}

__device__ __forceinline__ void fpub(unsigned* f, unsigned v) {
    __hip_atomic_store(f, v, __ATOMIC_RELAXED, __HIP_MEMORY_SCOPE_AGENT);
}
__device__ __forceinline__ void fwait(unsigned* f, unsigned v) {
    while (__hip_atomic_load(f, __ATOMIC_RELAXED, __HIP_MEMORY_SCOPE_AGENT) < v)
        __builtin_amdgcn_s_sleep(1);
}

// ---------------- params ----------------
struct SP {
    const int* tok; const float* emb; const float* pos;
    const float *l0w, *l0b, *l1w, *l1b, *l2w, *l2b;
    const float *tmk, *tmv, *tmr, *tf, *tdr;
    const float *ftmk, *ftmr, *low, *lob;
    const void *kw, *vw, *rw, *ow, *fkw, *fvw, *frw;
    float *xg, *xmid, *rwkv, *fk, *td;   // xg:[2][NGRP][2][DD]; xmid/rwkv:[NGRP][2][DD]; fk:[NGRP][2][FF]
    float *aa, *bb, *pp, *sxa, *sxf, *v1, *v2;
    float* XbT;          // [DD][TTOK]
    unsigned* bar;       // [grp*64] cnt/sense; +1024 done[]; +2048 rda[]
};

// ---------------- layer-wavefront persistent kernel (2 tokens / step) -------
template<bool F8>
__global__ __launch_bounds__(NTH, 4) void spike_wave(SP P) {
    const void* kw  = P.kw;
    const void* vw  = P.vw;
    const void* rw  = P.rw;
    const void* ow  = P.ow;
    const void* fkw = P.fkw;
    const void* fvw = P.fvw;
    const void* frw = P.frw;
    constexpr float XS = F8 ? XSC : 1.0f;

    __shared__ float xl[2][DD];                     // residual x / xmid, both tokens
    __shared__ float xs1[DD];                       // xa1 (A/B) then xf1 (C/D)
    __shared__ __align__(16) unsigned short xkb[2][DD], xvb[2][DD], xrb[2][DD];
    __shared__ __align__(16) unsigned short fklb[2][FF];
    __shared__ float red[16];
    __shared__ float kres[2][32], vres[2][32], rres[2][32];
    __shared__ float frl2[2][32];

    const int tid  = threadIdx.x;
    const int b    = blockIdx.x;
    const int wid  = tid >> 6;
    const int lane = tid & 63;
    const bool isHead = (b >= NGRP * GBLK);
    const int grp = isHead ? NGRP : (b / GBLK);
    const int gi  = isHead ? (b - NGRP * GBLK) : (b % GBLK);
    const unsigned gn = isHead ? (unsigned)NHEAD : (unsigned)GBLK;
    int c_beg = 0, c_end = 0, r_beg = 0, r_end = 0;
    if (!isHead) {
        c_beg = (gi * DD) / GBLK; c_end = ((gi + 1) * DD) / GBLK;
        r_beg = (gi * FF) / GBLK; r_end = ((gi + 1) * FF) / GBLK;
    }
    const int nch = c_end - c_beg;
    const int  ld = (isHead ? 0 : grp) * DD;
    const long rw0 = (long)(grp * 2) * DD;          // rwkv / xmid token-0 base
    const long fk0 = (long)(grp * 2) * FF;          // fk token-0 base

    unsigned* done = P.bar + 1024;
    unsigned* rda  = P.bar + 2048;

    // generic 2-token matvec pass over own channel slice (1 seg rows, 4-ch batch)
    auto mat2 = [&](const void* wm, const unsigned short* xb, float* o0, float* o1) {
        float x0r[16], x1r[16];
        xres(xb, lane, x0r);
        xres(xb + DD, lane, x1r);
        for (int c0 = c_beg + (wid << 2); c0 < c_end; c0 += 32) {
            WSeg<F8> w[4];
            #pragma unroll
            for (int k = 0; k < 4; ++k) {
                int c = c0 + k;
                wseg_load(w[k], wm, (long)ld + (c < c_end ? c : c0), 1, 0, lane);
            }
            #pragma unroll
            for (int k = 0; k < 4; ++k) {
                float d0 = wred(wseg_dot(w[k], x0r));
                float d1 = wred(wseg_dot(w[k], x1r));
                if (lane == 0 && c0 + k < c_end) {
                    o0[c0 + k - c_beg] = d0; o1[c0 + k - c_beg] = d1;
                }
            }
        }
    };

    unsigned sen = 0;

    // ---- init own layer state ----
    if (!isHead) {
        for (int c = c_beg + tid; c < c_end; c += NTH) {
            int si = ld + c;
            P.aa[si] = 0.f; P.bb[si] = 0.f; P.pp[si] = -1e30f;
            P.v1[si] = 0.f; P.v2[si] = 0.f;
            P.td[si] = -expf(P.tdr[si]);
            cst(&P.sxa[si], 0.f); cst(&P.sxf[si], 0.f);
        }
    }
    grpbar(P.bar, grp, gn, sen);

    #pragma unroll 1
    for (int s = 0; s < NSTEP; ++s) {
        const int t0 = 2 * (s - grp);
        const bool act = (t0 >= 0) && (t0 < TTOK);
        const unsigned wbuf = (unsigned)s & 1u, rbuf = wbuf ^ 1u;
        float* xgw = P.xg + (((size_t)wbuf * NGRP + (isHead ? 0 : grp)) * 2) * DD;
        const float* xgr = P.xg + (((size_t)rbuf * NGRP + (grp > 0 ? grp - 1 : 0)) * 2) * DD;

        // ================= stage A =================
        if (act) {
            if (isHead) {
                if (tid == 0) fwait(&done[NGRP - 1], (unsigned)s);
                __syncthreads();
                xl[0][tid] = cld(&xgr[tid]);       xl[0][tid + 512] = cld(&xgr[tid + 512]);
                xl[1][tid] = cld(&xgr[DD + tid]);  xl[1][tid + 512] = cld(&xgr[DD + tid + 512]);
                __syncthreads();
                float m0, rs0, m1, rs1;
                bstats(xl[0], red, m0, rs0);
                bstats(xl[1], red, m1, rs1);
                for (int cc = (gi << 7) + tid; cc < ((gi + 1) << 7); cc += NTH) {
                    P.XbT[(size_t)cc * TTOK + t0]     = (xl[0][cc] - m0) * rs0 * P.low[cc] + P.lob[cc];
                    P.XbT[(size_t)cc * TTOK + t0 + 1] = (xl[1][cc] - m1) * rs1 * P.low[cc] + P.lob[cc];
                }
            } else {
                if (grp == 0) {
                    int tk0 = P.tok[t0], tk1 = P.tok[t0 + 1];
                    #pragma unroll
                    for (int tk = 0; tk < 2; ++tk) {
                        size_t eb = (size_t)(tk ? tk1 : tk0) * DD;
                        size_t pb = (size_t)(t0 + tk) * DD;
                        float e0 = P.emb[eb + tid]       + P.pos[pb + tid];
                        float e1 = P.emb[eb + tid + 512] + P.pos[pb + tid + 512];
                        xl[tk][tid] = e0; xl[tk][tid + 512] = e1;
                        __syncthreads();
                        float m, rs; bstats(xl[tk], red, m, rs);
                        xl[tk][tid]       = (e0 - m) * rs * P.l0w[tid]       + P.l0b[tid];
                        xl[tk][tid + 512] = (e1 - m) * rs * P.l0w[tid + 512] + P.l0b[tid + 512];
                        __syncthreads();
                    }
                } else {
                    if (tid == 0) fwait(&done[grp - 1], (unsigned)s);
                    __syncthreads();
                    xl[0][tid] = cld(&xgr[tid]);       xl[0][tid + 512] = cld(&xgr[tid + 512]);
                    xl[1][tid] = cld(&xgr[DD + tid]);  xl[1][tid + 512] = cld(&xgr[DD + tid + 512]);
                    __syncthreads();
                }
                float m0, rs0, m1, rs1;
                bstats(xl[0], red, m0, rs0);
                bstats(xl[1], red, m1, rs1);
                {   // LN1 + mixes both tokens (thread owns elems 2tid, 2tid+1)
                    int i2 = tid << 1;
                    float2 w2 = *(const float2*)&P.l1w[ld + i2];
                    float2 b2 = *(const float2*)&P.l1b[ld + i2];
                    float2 uk = *(const float2*)&P.tmk[ld + i2];
                    float2 uv = *(const float2*)&P.tmv[ld + i2];
                    float2 ur = *(const float2*)&P.tmr[ld + i2];
                    // t0 (sx = stored state)
                    float a0 = (xl[0][i2]     - m0) * rs0 * w2.x + b2.x;
                    float a1 = (xl[0][i2 + 1] - m0) * rs0 * w2.y + b2.y;
                    float sx0 = cld(&P.sxa[ld + i2]), sx1 = cld(&P.sxa[ld + i2 + 1]);
                    ((unsigned*)xkb[0])[tid] = pack_bf2((a0*uk.x + sx0*(1.f-uk.x))*XS, (a1*uk.y + sx1*(1.f-uk.y))*XS);
                    ((unsigned*)xvb[0])[tid] = pack_bf2((a0*uv.x + sx0*(1.f-uv.x))*XS, (a1*uv.y + sx1*(1.f-uv.y))*XS);
                    ((unsigned*)xrb[0])[tid] = pack_bf2((a0*ur.x + sx0*(1.f-ur.x))*XS, (a1*ur.y + sx1*(1.f-ur.y))*XS);
                    // t1 (sx = xa(t0), thread-local!)
                    float c0v = (xl[1][i2]     - m1) * rs1 * w2.x + b2.x;
                    float c1v = (xl[1][i2 + 1] - m1) * rs1 * w2.y + b2.y;
                    xs1[i2] = c0v; xs1[i2 + 1] = c1v;      // xa1, for sxa update in B
                    ((unsigned*)xkb[1])[tid] = pack_bf2((c0v*uk.x + a0*(1.f-uk.x))*XS, (c1v*uk.y + a1*(1.f-uk.y))*XS);
                    ((unsigned*)xvb[1])[tid] = pack_bf2((c0v*uv.x + a0*(1.f-uv.x))*XS, (c1v*uv.y + a1*(1.f-uv.y))*XS);
                    ((unsigned*)xrb[1])[tid] = pack_bf2((c0v*ur.x + a0*(1.f-ur.x))*XS, (c1v*ur.y + a1*(1.f-ur.y))*XS);
                }
                __syncthreads();
                mat2(kw, xkb[0], kres[0], kres[1]);
                mat2(vw, xvb[0], vres[0], vres[1]);
                mat2(rw, xrb[0], rres[0], rres[1]);
                __syncthreads();
                if (tid < nch) {   // WKV, both tokens sequential
                    int c = c_beg + tid, si = ld + c;
                    float aa = P.aa[si], bb = P.bb[si], pp = P.pp[si];
                    float tf = P.tf[si], tdv = P.td[si];
                    #pragma unroll
                    for (int tk = 0; tk < 2; ++tk) {
                        float kk = kres[tk][tid], vv = vres[tk][tid], rr = rres[tk][tid];
                        float ww = tf + kk;
                        float q  = fmaxf(pp, ww);
                        float e1 = expf(pp - q), e2 = expf(ww - q);
                        float an = e1 * aa + e2 * vv, bn = e1 * bb + e2;
                        float ww2 = pp + tdv;
                        float q2  = fmaxf(ww2, kk);
                        float e1b = expf(ww2 - q2), e2b = expf(kk - q2);
                        aa = e1b * aa + e2b * vv;
                        bb = e1b * bb + e2b;
                        pp = q2;
                        float sg = 1.f / (1.f + expf(-rr));
                        cst(&P.rwkv[rw0 + tk * DD + c], sg * (an / bn));
                    }
                    P.aa[si] = aa; P.bb[si] = bb; P.pp[si] = pp;
                }
            }
        }
        grpbar(P.bar, grp, gn, sen);                       // bar1: A done
        if (gi == 0 && tid == 0) fpub(&rda[grp], (unsigned)(s + 1));

        // ================= stage B =================
        if (act && !isHead) {
            for (int c = c_beg + tid; c < c_end; c += NTH)
                cst(&P.sxa[ld + c], xs1[c]);               // sxa = xa(t1)
            {
                int i2 = tid << 1;
                ((unsigned*)xvb[0])[tid] = pack_bf2(cld(&P.rwkv[rw0 + i2]) * XS,
                                                    cld(&P.rwkv[rw0 + i2 + 1]) * XS);
                ((unsigned*)xvb[1])[tid] = pack_bf2(cld(&P.rwkv[rw0 + DD + i2]) * XS,
                                                    cld(&P.rwkv[rw0 + DD + i2 + 1]) * XS);
            }
            __syncthreads();
            mat2(ow, xvb[0], kres[0], kres[1]);            // o-dots into kres
            __syncthreads();
            if (tid < nch) {   // LIF(v1) both tokens
                int c = c_beg + tid, si = ld + c;
                float v1v = P.v1[si];
                float vn = v1v + (kres[0][tid] - v1v) * 0.5f;
                float sp0 = (vn >= 1.f) ? 1.f : 0.f;  v1v = vn * (1.f - sp0);
                vn = v1v + (kres[1][tid] - v1v) * 0.5f;
                float sp1 = (vn >= 1.f) ? 1.f : 0.f;  v1v = vn * (1.f - sp1);
                P.v1[si] = v1v;
                cst(&P.xmid[rw0 + c],      xl[0][c] + sp0);
                cst(&P.xmid[rw0 + DD + c], xl[1][c] + sp1);
            }
        }
        grpbar(P.bar, grp, gn, sen);                       // bar2: B done

        // ================= stage C =================
        if (act && !isHead) {
            xl[0][tid] = cld(&P.xmid[rw0 + tid]);       xl[0][tid + 512] = cld(&P.xmid[rw0 + tid + 512]);
            xl[1][tid] = cld(&P.xmid[rw0 + DD + tid]);  xl[1][tid + 512] = cld(&P.xmid[rw0 + DD + tid + 512]);
            __syncthreads();
            float m0, rs0, m1, rs1;
            bstats(xl[0], red, m0, rs0);
            bstats(xl[1], red, m1, rs1);
            {   // LN2 + FFN mixes both tokens
                int i2 = tid << 1;
                float2 w2 = *(const float2*)&P.l2w[ld + i2];
                float2 b2 = *(const float2*)&P.l2b[ld + i2];
                float2 uk = *(const float2*)&P.ftmk[ld + i2];
                float2 ur = *(const float2*)&P.ftmr[ld + i2];
                float f0 = (xl[0][i2]     - m0) * rs0 * w2.x + b2.x;
                float f1 = (xl[0][i2 + 1] - m0) * rs0 * w2.y + b2.y;
                float sx0 = cld(&P.sxf[ld + i2]), sx1 = cld(&P.sxf[ld + i2 + 1]);
                ((unsigned*)xkb[0])[tid] = pack_bf2((f0*uk.x + sx0*(1.f-uk.x))*XS, (f1*uk.y + sx1*(1.f-uk.y))*XS);
                ((unsigned*)xrb[0])[tid] = pack_bf2((f0*ur.x + sx0*(1.f-ur.x))*XS, (f1*ur.y + sx1*(1.f-ur.y))*XS);
                float g0 = (xl[1][i2]     - m1) * rs1 * w2.x + b2.x;
                float g1 = (xl[1][i2 + 1] - m1) * rs1 * w2.y + b2.y;
                xs1[i2] = g0; xs1[i2 + 1] = g1;            // xf1, for sxf update in D
                ((unsigned*)xkb[1])[tid] = pack_bf2((g0*uk.x + f0*(1.f-uk.x))*XS, (g1*uk.y + f1*(1.f-uk.y))*XS);
                ((unsigned*)xrb[1])[tid] = pack_bf2((g0*ur.x + f0*(1.f-ur.x))*XS, (g1*ur.y + f1*(1.f-ur.y))*XS);
            }
            __syncthreads();
            {   // fkw rows: 4-row batch, 2-token dots
                float x0r[16], x1r[16];
                xres(xkb[0], lane, x0r); xres(xkb[1], lane, x1r);
                for (int r0 = r_beg + (wid << 2); r0 < r_end; r0 += 32) {
                    WSeg<F8> w[4];
                    #pragma unroll
                    for (int k = 0; k < 4; ++k) {
                        int ri = r0 + k;
                        wseg_load(w[k], fkw, (long)grp * FF + (ri < r_end ? ri : r0), 1, 0, lane);
                    }
                    #pragma unroll
                    for (int k = 0; k < 4; ++k) {
                        if (r0 + k < r_end) {
                            float d0 = wred(wseg_dot(w[k], x0r));
                            float d1 = wred(wseg_dot(w[k], x1r));
                            if (lane == 0) {
                                float u0 = fmaxf(d0, 0.f); cst(&P.fk[fk0 + r0 + k], u0 * u0);
                                float u1 = fmaxf(d1, 0.f); cst(&P.fk[fk0 + FF + r0 + k], u1 * u1);
                            }
                        }
                    }
                }
            }
            mat2(frw, xrb[0], frl2[0], frl2[1]);           // raw fr dots (sigmoid in D)
        }
        grpbar(P.bar, grp, gn, sen);                       // bar3: C done

        // ================= stage D =================
        if (act && !isHead) {
            if (tid == 0 && s > 0) fwait(&rda[grp + 1], (unsigned)s);   // anti-dep on xg[wbuf]
            __syncthreads();
            for (int c = c_beg + tid; c < c_end; c += NTH)
                cst(&P.sxf[ld + c], xs1[c]);               // sxf = xf(t1)
            {   // stage fk pair -> fklb (bf16, XS folded); issue all loads first
                float la[4], lb[4], lc[4], ldv[4];
                #pragma unroll
                for (int j = 0; j < 4; ++j) {
                    int e = (tid << 1) + (j << 10);
                    la[j]  = cld(&P.fk[fk0 + e]);      lb[j]  = cld(&P.fk[fk0 + e + 1]);
                    lc[j]  = cld(&P.fk[fk0 + FF + e]); ldv[j] = cld(&P.fk[fk0 + FF + e + 1]);
                }
                #pragma unroll
                for (int j = 0; j < 4; ++j) {
                    ((unsigned*)fklb[0])[tid + (j << 9)] = pack_bf2(la[j] * XS, lb[j] * XS);
                    ((unsigned*)fklb[1])[tid + (j << 9)] = pack_bf2(lc[j] * XS, ldv[j] * XS);
                }
            }
            __syncthreads();
            {   // fvw: 2-channel batch × 4 segs, 2-token dots
                for (int c0 = c_beg + (wid << 1); c0 < c_end; c0 += 16) {
                    int c1 = c0 + 1; bool h1 = (c1 < c_end);
                    WSeg<F8> wa[4], wb[4];
                    #pragma unroll
                    for (int m = 0; m < 4; ++m) {
                        wseg_load(wa[m], fvw, (long)ld + c0, 4, m, lane);
                        wseg_load(wb[m], fvw, (long)ld + (h1 ? c1 : c0), 4, m, lane);
                    }
                    float a00 = 0.f, a01 = 0.f, a10 = 0.f, a11 = 0.f;
                    #pragma unroll
                    for (int m = 0; m < 4; ++m) {
                        float xf0[16], xf1[16];
                        xld8(fklb[0], (m << 7) + lane, xf0); xld8(fklb[0], (m << 7) + 64 + lane, xf0 + 8);
                        xld8(fklb[1], (m << 7) + lane, xf1); xld8(fklb[1], (m << 7) + 64 + lane, xf1 + 8);
                        a00 += wseg_dot(wa[m], xf0); a01 += wseg_dot(wa[m], xf1);
                        a10 += wseg_dot(wb[m], xf0); a11 += wseg_dot(wb[m], xf1);
                    }
                    a00 = wred(a00); a01 = wred(a01); a10 = wred(a10); a11 = wred(a11);
                    if (lane == 0) {
                        kres[0][c0 - c_beg] = a00; kres[1][c0 - c_beg] = a01;
                        if (h1) { kres[0][c1 - c_beg] = a10; kres[1][c1 - c_beg] = a11; }
                    }
                }
            }
            __syncthreads();
            if (tid < nch) {   // LIF(v2) + residual + rescale, both tokens
                int c = c_beg + tid, si = ld + c;
                float v2v = P.v2[si];
                float fr0 = 1.f / (1.f + expf(-frl2[0][tid]));
                float fr1 = 1.f / (1.f + expf(-frl2[1][tid]));
                float hh = fr0 * kres[0][tid];
                float vn = v2v + (hh - v2v) * 0.5f;
                float sp0 = (vn >= 1.f) ? 1.f : 0.f;  v2v = vn * (1.f - sp0);
                hh = fr1 * kres[1][tid];
                vn = v2v + (hh - v2v) * 0.5f;
                float sp1 = (vn >= 1.f) ? 1.f : 0.f;  v2v = vn * (1.f - sp1);
                P.v2[si] = v2v;
                float xn0 = xl[0][c] + sp0, xn1 = xl[1][c] + sp1;
                if (((grp + 1) % 6) == 0) { xn0 *= 0.5f; xn1 *= 0.5f; }
                cst(&xgw[c], xn0);
                cst(&xgw[DD + c], xn1);
            }
        }
        grpbar(P.bar, grp, gn, sen);                       // bar4: D done
        if (gi == 0 && tid == 0) fpub(&done[grp], (unsigned)(s + 1));
    }
}

// ---------------- VALU head: out[t][v] = sum_k head[v][k]*XbT[k][t] (f32 out) --
__global__ __launch_bounds__(256) void head_simple(const float* __restrict__ head,
                                                   const float* __restrict__ XbT,
                                                   float* __restrict__ out) {
    int wv   = __builtin_amdgcn_readfirstlane(threadIdx.x >> 6);
    int lane = threadIdx.x & 63;
    int v0   = (blockIdx.x * 4 + wv) * 8;
    if (v0 >= VV) return;
    const float* hp[8];
    #pragma unroll
    for (int r = 0; r < 8; ++r) {
        int v = v0 + r; if (v >= VV) v = VV - 1;
        hp[r] = head + (size_t)v * DD;
    }
    float a0[8], a1[8];
    #pragma unroll
    for (int r = 0; r < 8; ++r) { a0[r] = 0.f; a1[r] = 0.f; }
    #pragma unroll 4
    for (int k = 0; k < DD; ++k) {
        float2 x2 = *(const float2*)(XbT + (size_t)k * TTOK + lane * 2);
        #pragma unroll
        for (int r = 0; r < 8; ++r) {
            float hv = hp[r][k];
            a0[r] += hv * x2.x;
            a1[r] += hv * x2.y;
        }
    }
    int t0 = lane * 2, t1 = t0 + 1;
    #pragma unroll
    for (int r = 0; r < 8; ++r) {
        int v = v0 + r;
        if (v < VV) {
            out[(size_t)t0 * VV + v] = a0[r];
            out[(size_t)t1 * VV + v] = a1[r];
        }
    }
}

// ---------------- f32 -> fp8 (scaled ×WSC, swizzled) ----------------
__global__ void cvt_fp8(const float* __restrict__ s, unsigned char* __restrict__ d, long n) {
    long p4 = ((long)blockIdx.x * blockDim.x + threadIdx.x) * 4;
    long st = (long)gridDim.x * blockDim.x * 4;
    for (; p4 < n; p4 += st) {
        long seg = p4 >> 10;
        int  q   = (int)(p4 & 1023);
        int  u   = q >> 4, rem = q & 15, half = rem >> 3, j0 = rem & 7;
        long e = (seg << 10) + ((long)half << 9) + (u << 3) + j0;
        float4 f = *(const float4*)(s + e);
        f.x *= WSC; f.y *= WSC; f.z *= WSC; f.w *= WSC;
        *(unsigned*)(d + p4) = enc_fp8x4(f);
    }
}

// ---------------- host launch ----------------
extern "C" void kernel_launch(void* const* d_in, const int* in_sizes, int n_in,
                              void* d_out, int out_size, void* d_ws, size_t ws_size,
                              hipStream_t stream) {
    (void)in_sizes; (void)n_in; (void)out_size;
    char* base = (char*)d_ws;
    size_t off = 0;
    auto take = [&](size_t bytes) -> void* {
        void* p = base + off;
        off = (off + bytes + 255) & ~(size_t)255;
        return p;
    };
    unsigned* bar = (unsigned*)take(16384);
    float* xg   = (float*)take((size_t)2 * NGRP * 2 * DD * 4);   // [2][NGRP][2][DD]
    float* xmid = (float*)take((size_t)NGRP * 2 * DD * 4);
    float* rwkv = (float*)take((size_t)NGRP * 2 * DD * 4);
    float* fk   = (float*)take((size_t)NGRP * 2 * FF * 4);
    float* td   = (float*)take(LL * DD * 4);
    float* aa   = (float*)take(LL * DD * 4);
    float* bb   = (float*)take(LL * DD * 4);
    float* pp   = (float*)take(LL * DD * 4);
    float* sxa  = (float*)take(LL * DD * 4);
    float* sxf  = (float*)take(LL * DD * 4);
    float* v1   = (float*)take(LL * DD * 4);
    float* v2   = (float*)take(LL * DD * 4);
    float* XbT  = (float*)take((size_t)DD * TTOK * 4);
    size_t wDD = (size_t)LL * DD * DD;
    size_t wFD = (size_t)LL * FF * DD;
    unsigned char* kwb  = (unsigned char*)take(wDD);
    unsigned char* vwb  = (unsigned char*)take(wDD);
    unsigned char* rwb  = (unsigned char*)take(wDD);
    unsigned char* owb  = (unsigned char*)take(wDD);
    unsigned char* frwb = (unsigned char*)take(wDD);
    unsigned char* fkwb = (unsigned char*)take(wFD);
    unsigned char* fvwb = (unsigned char*)take(wFD);
    bool usef8 = (ws_size >= off);

    hipMemsetAsync(bar, 0, 16384, stream);

    SP P;
    P.tok = (const int*)d_in[0];
    P.emb = (const float*)d_in[1];
    P.pos = (const float*)d_in[2];
    P.l0w = (const float*)d_in[3];  P.l0b = (const float*)d_in[4];
    P.l1w = (const float*)d_in[5];  P.l1b = (const float*)d_in[6];
    P.l2w = (const float*)d_in[7];  P.l2b = (const float*)d_in[8];
    P.tmk = (const float*)d_in[9];  P.tmv = (const float*)d_in[10]; P.tmr = (const float*)d_in[11];
    P.tf  = (const float*)d_in[12]; P.tdr = (const float*)d_in[13];
    P.ftmk = (const float*)d_in[18]; P.ftmr = (const float*)d_in[19];
    P.low = (const float*)d_in[23]; P.lob = (const float*)d_in[24];
    P.xg = xg; P.xmid = xmid; P.rwkv = rwkv; P.fk = fk; P.td = td;
    P.aa = aa; P.bb = bb; P.pp = pp; P.sxa = sxa; P.sxf = sxf; P.v1 = v1; P.v2 = v2;
    P.XbT = XbT; P.bar = bar;

    if (usef8) {
        struct CV { const float* s; unsigned char* d; size_t n; } cv[7] = {
            {(const float*)d_in[14], kwb,  wDD}, {(const float*)d_in[15], vwb,  wDD},
            {(const float*)d_in[16], rwb,  wDD}, {(const float*)d_in[17], owb,  wDD},
            {(const float*)d_in[22], frwb, wDD},
            {(const float*)d_in[20], fkwb, wFD}, {(const float*)d_in[21], fvwb, wFD},
        };
        for (int i = 0; i < 7; ++i)
            cvt_fp8<<<dim3(2048), dim3(256), 0, stream>>>(cv[i].s, cv[i].d, (long)cv[i].n);
        P.kw = kwb; P.vw = vwb; P.rw = rwb; P.ow = owb; P.fkw = fkwb; P.fvw = fvwb; P.frw = frwb;
        spike_wave<true><<<dim3(NBLK), dim3(NTH), 0, stream>>>(P);
    } else {
        P.kw = d_in[14]; P.vw = d_in[15]; P.rw = d_in[16]; P.ow = d_in[17];
        P.fkw = d_in[20]; P.fvw = d_in[21]; P.frw = d_in[22];
        spike_wave<false><<<dim3(NBLK), dim3(NTH), 0, stream>>>(P);
    }
    int nwave = (VV + 7) / 8;
    int nblk  = (nwave + 3) / 4;
    head_simple<<<dim3(nblk), dim3(256), 0, stream>>>((const float*)d_in[25], XbT,
                                                      (float*)d_out);
}

// Round 11
// 5315.720 us; speedup vs baseline: 1.4897x; 1.4897x over previous
//
#include <hip/hip_runtime.h>
#include <hip/hip_bf16.h>
#include <hip/hip_fp8.h>

// ---------------- constants ----------------
#define LL   12
#define DD   1024
#define FF   4096
#define TTOK 128
#define VV   50257
#define NBLK 512
#define NTH  512
#define NGRP 12
#define GBLK 42                 // blocks per layer group (12*42=504, +8 head)
#define NHEAD (NBLK - NGRP * GBLK)
#define NSTEP (TTOK / 2 + NGRP) // 76 wavefront steps (2 tokens each)
#define WSC  256.0f             // fp8 encode scale
#define XSC  (1.0f / 256.0f)    // folded into x staging

// ---------------- coherent (cross-XCD) access helpers ----------------
__device__ __forceinline__ float cld(const float* p) {
    return __hip_atomic_load((float*)p, __ATOMIC_RELAXED, __HIP_MEMORY_SCOPE_AGENT);
}
__device__ __forceinline__ void cst(float* p, float v) {
    __hip_atomic_store(p, v, __ATOMIC_RELAXED, __HIP_MEMORY_SCOPE_AGENT);
}

// ---------------- small helpers ----------------
__device__ __host__ __forceinline__ unsigned short f2bf(float f) {
    union { float f; unsigned u; } x; x.f = f;
    unsigned r = x.u + 0x7fffu + ((x.u >> 16) & 1u);
    return (unsigned short)(r >> 16);
}

__device__ __forceinline__ unsigned pack_bf2(float a, float b) {
    return (unsigned)f2bf(a) | ((unsigned)f2bf(b) << 16);
}

__device__ __forceinline__ void ld8(const float* p, float* o) {
    float4 a = ((const float4*)p)[0], b = ((const float4*)p)[1];
    o[0]=a.x; o[1]=a.y; o[2]=a.z; o[3]=a.w; o[4]=b.x; o[5]=b.y; o[6]=b.z; o[7]=b.w;
}

__device__ __forceinline__ void bf8unpack(uint4 u, float* o) {
    union { unsigned u; float f; } t;
    t.u = u.x << 16;         o[0] = t.f;
    t.u = u.x & 0xffff0000u; o[1] = t.f;
    t.u = u.y << 16;         o[2] = t.f;
    t.u = u.y & 0xffff0000u; o[3] = t.f;
    t.u = u.z << 16;         o[4] = t.f;
    t.u = u.z & 0xffff0000u; o[5] = t.f;
    t.u = u.w << 16;         o[6] = t.f;
    t.u = u.w & 0xffff0000u; o[7] = t.f;
}

__device__ __forceinline__ void xld8(const unsigned short* x, int chunk, float* o) {
    uint4 u = *reinterpret_cast<const uint4*>(x + (chunk << 3));
    bf8unpack(u, o);
}
// resident 16-elem x segment for lane (seg layout: elems 8l.. & 512+8l..)
__device__ __forceinline__ void xres(const unsigned short* xb, int lane, float* o) {
    xld8(xb, lane, o); xld8(xb, lane + 64, o + 8);
}

// ---------------- fp8 e4m3 decode/encode ----------------
typedef __attribute__((ext_vector_type(2))) float f32x2_t;

__device__ __forceinline__ void fp8x4(unsigned v, float* o) {
#if __has_builtin(__builtin_amdgcn_cvt_pk_f32_fp8)
    f32x2_t a = __builtin_amdgcn_cvt_pk_f32_fp8(v, false);
    f32x2_t b = __builtin_amdgcn_cvt_pk_f32_fp8(v, true);
    o[0] = a[0]; o[1] = a[1]; o[2] = b[0]; o[3] = b[1];
#else
    #pragma unroll
    for (int i = 0; i < 4; ++i) {
        __hip_fp8_e4m3 t; t.__x = (__hip_fp8_storage_t)((v >> (8 * i)) & 0xffu);
        o[i] = (float)t;
    }
#endif
}

__device__ __forceinline__ unsigned enc_fp8x4(float4 f) {
#if __has_builtin(__builtin_amdgcn_cvt_pk_fp8_f32)
    int d = 0;
    d = __builtin_amdgcn_cvt_pk_fp8_f32(f.x, f.y, d, false);
    d = __builtin_amdgcn_cvt_pk_fp8_f32(f.z, f.w, d, true);
    return (unsigned)d;
#else
    __hip_fp8_e4m3 a(f.x), b(f.y), c(f.z), e(f.w);
    return (unsigned)a.__x | ((unsigned)b.__x << 8) |
           ((unsigned)c.__x << 16) | ((unsigned)e.__x << 24);
#endif
}

__device__ __forceinline__ float dot16u(uint4 w, const float* x) {
    float wf[4], s;
    fp8x4(w.x, wf); s  = wf[0]*x[0] +wf[1]*x[1] +wf[2]*x[2] +wf[3]*x[3];
    fp8x4(w.y, wf); s += wf[0]*x[4] +wf[1]*x[5] +wf[2]*x[6] +wf[3]*x[7];
    fp8x4(w.z, wf); s += wf[0]*x[8] +wf[1]*x[9] +wf[2]*x[10]+wf[3]*x[11];
    fp8x4(w.w, wf); s += wf[0]*x[12]+wf[1]*x[13]+wf[2]*x[14]+wf[3]*x[15];
    return s;
}
__device__ __forceinline__ float dot16f(const float* w, const float* x) {
    float s = 0.f;
    #pragma unroll
    for (int i = 0; i < 16; ++i) s += w[i] * x[i];
    return s;
}

// generic 16-elem weight segment (F8 = packed uint4; f32 = 16 floats)
template<bool F8> struct WSeg;
template<> struct WSeg<true>  { uint4 v; };
template<> struct WSeg<false> { float f[16]; };

__device__ __forceinline__ void wseg_load(WSeg<true>& d, const void* w, long row,
                                          int segs, int m, int lane) {
    d.v = *(const uint4*)((const unsigned char*)w + (((row * segs + m) << 10) + (lane << 4)));
}
__device__ __forceinline__ void wseg_load(WSeg<false>& d, const void* w, long row,
                                          int segs, int m, int lane) {
    const float* p = (const float*)w + ((long)(row * segs + m) << 10);
    ld8(p + (lane << 3), d.f);
    ld8(p + 512 + (lane << 3), d.f + 8);
}
__device__ __forceinline__ float wseg_dot(const WSeg<true>& d, const float* x) { return dot16u(d.v, x); }
__device__ __forceinline__ float wseg_dot(const WSeg<false>& d, const float* x) { return dot16f(d.f, x); }

__device__ __forceinline__ float wred(float s) {
    #pragma unroll
    for (int o = 32; o; o >>= 1) s += __shfl_xor(s, o, 64);
    return s;
}

// block stats over x[1024] (512 threads): mean + rstd
__device__ __forceinline__ void bstats(const float* x, float* red, float& m, float& rs) {
    int tid = threadIdx.x;
    float a = x[tid], b = x[tid + 512];
    float s0 = a + b, s1 = a*a + b*b;
    #pragma unroll
    for (int o = 32; o; o >>= 1) { s0 += __shfl_xor(s0, o, 64); s1 += __shfl_xor(s1, o, 64); }
    if ((tid & 63) == 0) { red[(tid >> 6) * 2] = s0; red[(tid >> 6) * 2 + 1] = s1; }
    __syncthreads();
    float ms = 0.f, qs = 0.f;
    #pragma unroll
    for (int w = 0; w < 8; ++w) { ms += red[w * 2]; qs += red[w * 2 + 1]; }
    ms *= (1.f / 1024.f); qs *= (1.f / 1024.f);
    m = ms; rs = rsqrtf(qs - ms * ms + 1e-5f);
    __syncthreads();
}

// ---------------- group barrier (flat counter, sense-reversing) --------------
__device__ __forceinline__ void grpbar(unsigned* bar, int grp, unsigned n, unsigned& sen) {
    __syncthreads();
    if (threadIdx.x == 0) {
        unsigned s = sen ^ 1u;
        unsigned* cnt = &bar[grp * 64];
        unsigned* sns = &bar[grp * 64 + 32];
        unsigned prev = __hip_atomic_fetch_add(cnt, 1u, __ATOMIC_RELAXED, __HIP_MEMORY_SCOPE_AGENT);
        if (prev == n - 1u) {
            __hip_atomic_store(cnt, 0u, __ATOMIC_RELAXED, __HIP_MEMORY_SCOPE_AGENT);
            asm volatile("s_waitcnt vmcnt(0)" ::: "memory");
            __hip_atomic_store(sns, s, __ATOMIC_RELAXED, __HIP_MEMORY_SCOPE_AGENT);
        } else {
            while (__hip_atomic_load(sns, __ATOMIC_RELAXED, __HIP_MEMORY_SCOPE_AGENT) != s)
                __builtin_amdgcn_s_sleep(1);
        }
    }
    sen ^= 1u;
    __syncthreads();
}

__device__ __forceinline__ void fpub(unsigned* f, unsigned v) {
    __hip_atomic_store(f, v, __ATOMIC_RELAXED, __HIP_MEMORY_SCOPE_AGENT);
}
__device__ __forceinline__ void fwait(unsigned* f, unsigned v) {
    while (__hip_atomic_load(f, __ATOMIC_RELAXED, __HIP_MEMORY_SCOPE_AGENT) < v)
        __builtin_amdgcn_s_sleep(1);
}

// ---------------- params ----------------
struct SP {
    const int* tok; const float* emb; const float* pos;
    const float *l0w, *l0b, *l1w, *l1b, *l2w, *l2b;
    const float *tmk, *tmv, *tmr, *tf, *tdr;
    const float *ftmk, *ftmr, *low, *lob;
    const void *kw, *vw, *rw, *ow, *fkw, *fvw, *frw;
    float *xg, *xmid, *rwkv, *fk, *td;   // xg:[2][NGRP][2][DD]; xmid/rwkv:[NGRP][2][DD]; fk:[NGRP][2][FF]
    float *aa, *bb, *pp, *sxa, *sxf, *v1, *v2;
    float* XbT;          // [DD][TTOK]
    unsigned* bar;       // [grp*64] cnt/sense; +1024 done[]; +2048 rda[]
};

// ---------------- layer-wavefront persistent kernel (2 tokens / step) -------
template<bool F8>
__global__ __launch_bounds__(NTH, 4) void spike_wave(SP P) {
    const void* kw  = P.kw;
    const void* vw  = P.vw;
    const void* rw  = P.rw;
    const void* ow  = P.ow;
    const void* fkw = P.fkw;
    const void* fvw = P.fvw;
    const void* frw = P.frw;
    constexpr float XS = F8 ? XSC : 1.0f;

    __shared__ float xl[2][DD];                     // residual x / xmid, both tokens
    __shared__ float xs1[DD];                       // xa1 (A/B) then xf1 (C/D)
    __shared__ __align__(16) unsigned short xkb[2][DD], xvb[2][DD], xrb[2][DD];
    __shared__ __align__(16) unsigned short fklb[2][FF];
    __shared__ float red[16];
    __shared__ float kres[2][32], vres[2][32], rres[2][32];
    __shared__ float frl2[2][32];

    const int tid  = threadIdx.x;
    const int b    = blockIdx.x;
    const int wid  = tid >> 6;
    const int lane = tid & 63;
    const bool isHead = (b >= NGRP * GBLK);
    const int grp = isHead ? NGRP : (b / GBLK);
    const int gi  = isHead ? (b - NGRP * GBLK) : (b % GBLK);
    const unsigned gn = isHead ? (unsigned)NHEAD : (unsigned)GBLK;
    int c_beg = 0, c_end = 0, r_beg = 0, r_end = 0;
    if (!isHead) {
        c_beg = (gi * DD) / GBLK; c_end = ((gi + 1) * DD) / GBLK;
        r_beg = (gi * FF) / GBLK; r_end = ((gi + 1) * FF) / GBLK;
    }
    const int nch = c_end - c_beg;
    const int  ld = (isHead ? 0 : grp) * DD;
    const long rw0 = (long)(grp * 2) * DD;          // rwkv / xmid token-0 base
    const long fk0 = (long)(grp * 2) * FF;          // fk token-0 base

    unsigned* done = P.bar + 1024;
    unsigned* rda  = P.bar + 2048;

    // generic 2-token matvec pass over own channel slice (1-seg rows, 4-ch batch)
    auto mat2 = [&](const void* wm, const unsigned short* xb, float* o0, float* o1) {
        float x0r[16], x1r[16];
        xres(xb, lane, x0r);
        xres(xb + DD, lane, x1r);
        for (int c0 = c_beg + (wid << 2); c0 < c_end; c0 += 32) {
            WSeg<F8> w[4];
            #pragma unroll
            for (int k = 0; k < 4; ++k) {
                int c = c0 + k;
                wseg_load(w[k], wm, (long)ld + (c < c_end ? c : c0), 1, 0, lane);
            }
            #pragma unroll
            for (int k = 0; k < 4; ++k) {
                float d0 = wred(wseg_dot(w[k], x0r));
                float d1 = wred(wseg_dot(w[k], x1r));
                if (lane == 0 && c0 + k < c_end) {
                    o0[c0 + k - c_beg] = d0; o1[c0 + k - c_beg] = d1;
                }
            }
        }
    };

    unsigned sen = 0;

    // ---- init own layer state ----
    if (!isHead) {
        for (int c = c_beg + tid; c < c_end; c += NTH) {
            int si = ld + c;
            P.aa[si] = 0.f; P.bb[si] = 0.f; P.pp[si] = -1e30f;
            P.v1[si] = 0.f; P.v2[si] = 0.f;
            P.td[si] = -expf(P.tdr[si]);
            cst(&P.sxa[si], 0.f); cst(&P.sxf[si], 0.f);
        }
    }
    grpbar(P.bar, grp, gn, sen);

    #pragma unroll 1
    for (int s = 0; s < NSTEP; ++s) {
        const int t0 = 2 * (s - grp);
        const bool act = (t0 >= 0) && (t0 < TTOK);
        const unsigned wbuf = (unsigned)s & 1u, rbuf = wbuf ^ 1u;
        float* xgw = P.xg + (((size_t)wbuf * NGRP + (isHead ? 0 : grp)) * 2) * DD;
        const float* xgr = P.xg + (((size_t)rbuf * NGRP + (grp > 0 ? grp - 1 : 0)) * 2) * DD;

        // ================= stage A =================
        if (act) {
            if (isHead) {
                if (tid == 0) fwait(&done[NGRP - 1], (unsigned)s);
                __syncthreads();
                xl[0][tid] = cld(&xgr[tid]);       xl[0][tid + 512] = cld(&xgr[tid + 512]);
                xl[1][tid] = cld(&xgr[DD + tid]);  xl[1][tid + 512] = cld(&xgr[DD + tid + 512]);
                __syncthreads();
                float m0, rs0, m1, rs1;
                bstats(xl[0], red, m0, rs0);
                bstats(xl[1], red, m1, rs1);
                for (int cc = (gi << 7) + tid; cc < ((gi + 1) << 7); cc += NTH) {
                    P.XbT[(size_t)cc * TTOK + t0]     = (xl[0][cc] - m0) * rs0 * P.low[cc] + P.lob[cc];
                    P.XbT[(size_t)cc * TTOK + t0 + 1] = (xl[1][cc] - m1) * rs1 * P.low[cc] + P.lob[cc];
                }
            } else {
                if (grp == 0) {
                    int tk0 = P.tok[t0], tk1 = P.tok[t0 + 1];
                    #pragma unroll
                    for (int tk = 0; tk < 2; ++tk) {
                        size_t eb = (size_t)(tk ? tk1 : tk0) * DD;
                        size_t pb = (size_t)(t0 + tk) * DD;
                        float e0 = P.emb[eb + tid]       + P.pos[pb + tid];
                        float e1 = P.emb[eb + tid + 512] + P.pos[pb + tid + 512];
                        xl[tk][tid] = e0; xl[tk][tid + 512] = e1;
                        __syncthreads();
                        float m, rs; bstats(xl[tk], red, m, rs);
                        xl[tk][tid]       = (e0 - m) * rs * P.l0w[tid]       + P.l0b[tid];
                        xl[tk][tid + 512] = (e1 - m) * rs * P.l0w[tid + 512] + P.l0b[tid + 512];
                        __syncthreads();
                    }
                } else {
                    if (tid == 0) fwait(&done[grp - 1], (unsigned)s);
                    __syncthreads();
                    xl[0][tid] = cld(&xgr[tid]);       xl[0][tid + 512] = cld(&xgr[tid + 512]);
                    xl[1][tid] = cld(&xgr[DD + tid]);  xl[1][tid + 512] = cld(&xgr[DD + tid + 512]);
                    __syncthreads();
                }
                float m0, rs0, m1, rs1;
                bstats(xl[0], red, m0, rs0);
                bstats(xl[1], red, m1, rs1);
                {   // LN1 + mixes both tokens (thread owns elems 2tid, 2tid+1)
                    int i2 = tid << 1;
                    float2 w2 = *(const float2*)&P.l1w[ld + i2];
                    float2 b2 = *(const float2*)&P.l1b[ld + i2];
                    float2 uk = *(const float2*)&P.tmk[ld + i2];
                    float2 uv = *(const float2*)&P.tmv[ld + i2];
                    float2 ur = *(const float2*)&P.tmr[ld + i2];
                    // t0 (sx = stored state)
                    float a0 = (xl[0][i2]     - m0) * rs0 * w2.x + b2.x;
                    float a1 = (xl[0][i2 + 1] - m0) * rs0 * w2.y + b2.y;
                    float sx0 = cld(&P.sxa[ld + i2]), sx1 = cld(&P.sxa[ld + i2 + 1]);
                    ((unsigned*)xkb[0])[tid] = pack_bf2((a0*uk.x + sx0*(1.f-uk.x))*XS, (a1*uk.y + sx1*(1.f-uk.y))*XS);
                    ((unsigned*)xvb[0])[tid] = pack_bf2((a0*uv.x + sx0*(1.f-uv.x))*XS, (a1*uv.y + sx1*(1.f-uv.y))*XS);
                    ((unsigned*)xrb[0])[tid] = pack_bf2((a0*ur.x + sx0*(1.f-ur.x))*XS, (a1*ur.y + sx1*(1.f-ur.y))*XS);
                    // t1 (sx = xa(t0), thread-local!)
                    float c0v = (xl[1][i2]     - m1) * rs1 * w2.x + b2.x;
                    float c1v = (xl[1][i2 + 1] - m1) * rs1 * w2.y + b2.y;
                    xs1[i2] = c0v; xs1[i2 + 1] = c1v;      // xa1, for sxa update in B
                    ((unsigned*)xkb[1])[tid] = pack_bf2((c0v*uk.x + a0*(1.f-uk.x))*XS, (c1v*uk.y + a1*(1.f-uk.y))*XS);
                    ((unsigned*)xvb[1])[tid] = pack_bf2((c0v*uv.x + a0*(1.f-uv.x))*XS, (c1v*uv.y + a1*(1.f-uv.y))*XS);
                    ((unsigned*)xrb[1])[tid] = pack_bf2((c0v*ur.x + a0*(1.f-ur.x))*XS, (c1v*ur.y + a1*(1.f-ur.y))*XS);
                }
                __syncthreads();
                mat2(kw, xkb[0], kres[0], kres[1]);
                mat2(vw, xvb[0], vres[0], vres[1]);
                mat2(rw, xrb[0], rres[0], rres[1]);
                __syncthreads();
                if (tid < nch) {   // WKV, both tokens sequential
                    int c = c_beg + tid, si = ld + c;
                    float aa = P.aa[si], bb = P.bb[si], pp = P.pp[si];
                    float tf = P.tf[si], tdv = P.td[si];
                    #pragma unroll
                    for (int tk = 0; tk < 2; ++tk) {
                        float kk = kres[tk][tid], vv = vres[tk][tid], rr = rres[tk][tid];
                        float ww = tf + kk;
                        float q  = fmaxf(pp, ww);
                        float e1 = expf(pp - q), e2 = expf(ww - q);
                        float an = e1 * aa + e2 * vv, bn = e1 * bb + e2;
                        float ww2 = pp + tdv;
                        float q2  = fmaxf(ww2, kk);
                        float e1b = expf(ww2 - q2), e2b = expf(kk - q2);
                        aa = e1b * aa + e2b * vv;
                        bb = e1b * bb + e2b;
                        pp = q2;
                        float sg = 1.f / (1.f + expf(-rr));
                        cst(&P.rwkv[rw0 + tk * DD + c], sg * (an / bn));
                    }
                    P.aa[si] = aa; P.bb[si] = bb; P.pp[si] = pp;
                }
            }
        }
        grpbar(P.bar, grp, gn, sen);                       // bar1: A done
        if (gi == 0 && tid == 0) fpub(&rda[grp], (unsigned)(s + 1));

        // ================= stage B =================
        if (act && !isHead) {
            for (int c = c_beg + tid; c < c_end; c += NTH)
                cst(&P.sxa[ld + c], xs1[c]);               // sxa = xa(t1)
            {
                int i2 = tid << 1;
                ((unsigned*)xvb[0])[tid] = pack_bf2(cld(&P.rwkv[rw0 + i2]) * XS,
                                                    cld(&P.rwkv[rw0 + i2 + 1]) * XS);
                ((unsigned*)xvb[1])[tid] = pack_bf2(cld(&P.rwkv[rw0 + DD + i2]) * XS,
                                                    cld(&P.rwkv[rw0 + DD + i2 + 1]) * XS);
            }
            __syncthreads();
            mat2(ow, xvb[0], kres[0], kres[1]);            // o-dots into kres
            __syncthreads();
            if (tid < nch) {   // LIF(v1) both tokens
                int c = c_beg + tid, si = ld + c;
                float v1v = P.v1[si];
                float vn = v1v + (kres[0][tid] - v1v) * 0.5f;
                float sp0 = (vn >= 1.f) ? 1.f : 0.f;  v1v = vn * (1.f - sp0);
                vn = v1v + (kres[1][tid] - v1v) * 0.5f;
                float sp1 = (vn >= 1.f) ? 1.f : 0.f;  v1v = vn * (1.f - sp1);
                P.v1[si] = v1v;
                cst(&P.xmid[rw0 + c],      xl[0][c] + sp0);
                cst(&P.xmid[rw0 + DD + c], xl[1][c] + sp1);
            }
        }
        grpbar(P.bar, grp, gn, sen);                       // bar2: B done

        // ================= stage C =================
        if (act && !isHead) {
            xl[0][tid] = cld(&P.xmid[rw0 + tid]);       xl[0][tid + 512] = cld(&P.xmid[rw0 + tid + 512]);
            xl[1][tid] = cld(&P.xmid[rw0 + DD + tid]);  xl[1][tid + 512] = cld(&P.xmid[rw0 + DD + tid + 512]);
            __syncthreads();
            float m0, rs0, m1, rs1;
            bstats(xl[0], red, m0, rs0);
            bstats(xl[1], red, m1, rs1);
            {   // LN2 + FFN mixes both tokens
                int i2 = tid << 1;
                float2 w2 = *(const float2*)&P.l2w[ld + i2];
                float2 b2 = *(const float2*)&P.l2b[ld + i2];
                float2 uk = *(const float2*)&P.ftmk[ld + i2];
                float2 ur = *(const float2*)&P.ftmr[ld + i2];
                float f0 = (xl[0][i2]     - m0) * rs0 * w2.x + b2.x;
                float f1 = (xl[0][i2 + 1] - m0) * rs0 * w2.y + b2.y;
                float sx0 = cld(&P.sxf[ld + i2]), sx1 = cld(&P.sxf[ld + i2 + 1]);
                ((unsigned*)xkb[0])[tid] = pack_bf2((f0*uk.x + sx0*(1.f-uk.x))*XS, (f1*uk.y + sx1*(1.f-uk.y))*XS);
                ((unsigned*)xrb[0])[tid] = pack_bf2((f0*ur.x + sx0*(1.f-ur.x))*XS, (f1*ur.y + sx1*(1.f-ur.y))*XS);
                float g0 = (xl[1][i2]     - m1) * rs1 * w2.x + b2.x;
                float g1 = (xl[1][i2 + 1] - m1) * rs1 * w2.y + b2.y;
                xs1[i2] = g0; xs1[i2 + 1] = g1;            // xf1, for sxf update in D
                ((unsigned*)xkb[1])[tid] = pack_bf2((g0*uk.x + f0*(1.f-uk.x))*XS, (g1*uk.y + f1*(1.f-uk.y))*XS);
                ((unsigned*)xrb[1])[tid] = pack_bf2((g0*ur.x + f0*(1.f-ur.x))*XS, (g1*ur.y + f1*(1.f-ur.y))*XS);
            }
            __syncthreads();
            {   // fkw rows: 4-row batch, 2-token dots
                float x0r[16], x1r[16];
                xres(xkb[0], lane, x0r); xres(xkb[1], lane, x1r);
                for (int r0 = r_beg + (wid << 2); r0 < r_end; r0 += 32) {
                    WSeg<F8> w[4];
                    #pragma unroll
                    for (int k = 0; k < 4; ++k) {
                        int ri = r0 + k;
                        wseg_load(w[k], fkw, (long)grp * FF + (ri < r_end ? ri : r0), 1, 0, lane);
                    }
                    #pragma unroll
                    for (int k = 0; k < 4; ++k) {
                        if (r0 + k < r_end) {
                            float d0 = wred(wseg_dot(w[k], x0r));
                            float d1 = wred(wseg_dot(w[k], x1r));
                            if (lane == 0) {
                                float u0 = fmaxf(d0, 0.f); cst(&P.fk[fk0 + r0 + k], u0 * u0);
                                float u1 = fmaxf(d1, 0.f); cst(&P.fk[fk0 + FF + r0 + k], u1 * u1);
                            }
                        }
                    }
                }
            }
            mat2(frw, xrb[0], frl2[0], frl2[1]);           // raw fr dots (sigmoid in D)
        }
        grpbar(P.bar, grp, gn, sen);                       // bar3: C done

        // ================= stage D =================
        if (act && !isHead) {
            if (tid == 0 && s > 0) fwait(&rda[grp + 1], (unsigned)s);   // anti-dep on xg[wbuf]
            __syncthreads();
            for (int c = c_beg + tid; c < c_end; c += NTH)
                cst(&P.sxf[ld + c], xs1[c]);               // sxf = xf(t1)
            {   // stage fk pair -> fklb (bf16, XS folded); issue all loads first
                float la[4], lb[4], lc[4], ldv[4];
                #pragma unroll
                for (int j = 0; j < 4; ++j) {
                    int e = (tid << 1) + (j << 10);
                    la[j]  = cld(&P.fk[fk0 + e]);      lb[j]  = cld(&P.fk[fk0 + e + 1]);
                    lc[j]  = cld(&P.fk[fk0 + FF + e]); ldv[j] = cld(&P.fk[fk0 + FF + e + 1]);
                }
                #pragma unroll
                for (int j = 0; j < 4; ++j) {
                    ((unsigned*)fklb[0])[tid + (j << 9)] = pack_bf2(la[j] * XS, lb[j] * XS);
                    ((unsigned*)fklb[1])[tid + (j << 9)] = pack_bf2(lc[j] * XS, ldv[j] * XS);
                }
            }
            __syncthreads();
            {   // fvw: m-OUTER accumulation (register-pressure bounded, no spill).
                // Per m: 4 weight segs (transient) + one 32-float fk pair; accs persist.
                for (int c0 = c_beg + (wid << 2); c0 < c_end; c0 += 32) {
                    float acc0[4], acc1[4];
                    #pragma unroll
                    for (int k = 0; k < 4; ++k) { acc0[k] = 0.f; acc1[k] = 0.f; }
                    #pragma unroll 1
                    for (int m = 0; m < 4; ++m) {
                        WSeg<F8> w[4];
                        #pragma unroll
                        for (int k = 0; k < 4; ++k) {
                            int c = c0 + k;
                            wseg_load(w[k], fvw, (long)ld + (c < c_end ? c : c0), 4, m, lane);
                        }
                        float xf0[16], xf1[16];
                        xld8(fklb[0], (m << 7) + lane, xf0);
                        xld8(fklb[0], (m << 7) + 64 + lane, xf0 + 8);
                        xld8(fklb[1], (m << 7) + lane, xf1);
                        xld8(fklb[1], (m << 7) + 64 + lane, xf1 + 8);
                        #pragma unroll
                        for (int k = 0; k < 4; ++k) {
                            acc0[k] += wseg_dot(w[k], xf0);
                            acc1[k] += wseg_dot(w[k], xf1);
                        }
                    }
                    #pragma unroll
                    for (int k = 0; k < 4; ++k) {
                        float f0 = wred(acc0[k]), f1 = wred(acc1[k]);
                        if (lane == 0 && c0 + k < c_end) {
                            kres[0][c0 + k - c_beg] = f0;
                            kres[1][c0 + k - c_beg] = f1;
                        }
                    }
                }
            }
            __syncthreads();
            if (tid < nch) {   // LIF(v2) + residual + rescale, both tokens
                int c = c_beg + tid, si = ld + c;
                float v2v = P.v2[si];
                float fr0 = 1.f / (1.f + expf(-frl2[0][tid]));
                float fr1 = 1.f / (1.f + expf(-frl2[1][tid]));
                float hh = fr0 * kres[0][tid];
                float vn = v2v + (hh - v2v) * 0.5f;
                float sp0 = (vn >= 1.f) ? 1.f : 0.f;  v2v = vn * (1.f - sp0);
                hh = fr1 * kres[1][tid];
                vn = v2v + (hh - v2v) * 0.5f;
                float sp1 = (vn >= 1.f) ? 1.f : 0.f;  v2v = vn * (1.f - sp1);
                P.v2[si] = v2v;
                float xn0 = xl[0][c] + sp0, xn1 = xl[1][c] + sp1;
                if (((grp + 1) % 6) == 0) { xn0 *= 0.5f; xn1 *= 0.5f; }
                cst(&xgw[c], xn0);
                cst(&xgw[DD + c], xn1);
            }
        }
        grpbar(P.bar, grp, gn, sen);                       // bar4: D done
        if (gi == 0 && tid == 0) fpub(&done[grp], (unsigned)(s + 1));
    }
}

// ---------------- VALU head: out[t][v] = sum_k head[v][k]*XbT[k][t] (f32 out) --
__global__ __launch_bounds__(256) void head_simple(const float* __restrict__ head,
                                                   const float* __restrict__ XbT,
                                                   float* __restrict__ out) {
    int wv   = __builtin_amdgcn_readfirstlane(threadIdx.x >> 6);
    int lane = threadIdx.x & 63;
    int v0   = (blockIdx.x * 4 + wv) * 8;
    if (v0 >= VV) return;
    const float* hp[8];
    #pragma unroll
    for (int r = 0; r < 8; ++r) {
        int v = v0 + r; if (v >= VV) v = VV - 1;
        hp[r] = head + (size_t)v * DD;
    }
    float a0[8], a1[8];
    #pragma unroll
    for (int r = 0; r < 8; ++r) { a0[r] = 0.f; a1[r] = 0.f; }
    #pragma unroll 4
    for (int k = 0; k < DD; ++k) {
        float2 x2 = *(const float2*)(XbT + (size_t)k * TTOK + lane * 2);
        #pragma unroll
        for (int r = 0; r < 8; ++r) {
            float hv = hp[r][k];
            a0[r] += hv * x2.x;
            a1[r] += hv * x2.y;
        }
    }
    int t0 = lane * 2, t1 = t0 + 1;
    #pragma unroll
    for (int r = 0; r < 8; ++r) {
        int v = v0 + r;
        if (v < VV) {
            out[(size_t)t0 * VV + v] = a0[r];
            out[(size_t)t1 * VV + v] = a1[r];
        }
    }
}

// ---------------- f32 -> fp8 (scaled ×WSC, swizzled) ----------------
__global__ void cvt_fp8(const float* __restrict__ s, unsigned char* __restrict__ d, long n) {
    long p4 = ((long)blockIdx.x * blockDim.x + threadIdx.x) * 4;
    long st = (long)gridDim.x * blockDim.x * 4;
    for (; p4 < n; p4 += st) {
        long seg = p4 >> 10;
        int  q   = (int)(p4 & 1023);
        int  u   = q >> 4, rem = q & 15, half = rem >> 3, j0 = rem & 7;
        long e = (seg << 10) + ((long)half << 9) + (u << 3) + j0;
        float4 f = *(const float4*)(s + e);
        f.x *= WSC; f.y *= WSC; f.z *= WSC; f.w *= WSC;
        *(unsigned*)(d + p4) = enc_fp8x4(f);
    }
}

// ---------------- host launch ----------------
extern "C" void kernel_launch(void* const* d_in, const int* in_sizes, int n_in,
                              void* d_out, int out_size, void* d_ws, size_t ws_size,
                              hipStream_t stream) {
    (void)in_sizes; (void)n_in; (void)out_size;
    char* base = (char*)d_ws;
    size_t off = 0;
    auto take = [&](size_t bytes) -> void* {
        void* p = base + off;
        off = (off + bytes + 255) & ~(size_t)255;
        return p;
    };
    unsigned* bar = (unsigned*)take(16384);
    float* xg   = (float*)take((size_t)2 * NGRP * 2 * DD * 4);   // [2][NGRP][2][DD]
    float* xmid = (float*)take((size_t)NGRP * 2 * DD * 4);
    float* rwkv = (float*)take((size_t)NGRP * 2 * DD * 4);
    float* fk   = (float*)take((size_t)NGRP * 2 * FF * 4);
    float* td   = (float*)take(LL * DD * 4);
    float* aa   = (float*)take(LL * DD * 4);
    float* bb   = (float*)take(LL * DD * 4);
    float* pp   = (float*)take(LL * DD * 4);
    float* sxa  = (float*)take(LL * DD * 4);
    float* sxf  = (float*)take(LL * DD * 4);
    float* v1   = (float*)take(LL * DD * 4);
    float* v2   = (float*)take(LL * DD * 4);
    float* XbT  = (float*)take((size_t)DD * TTOK * 4);
    size_t wDD = (size_t)LL * DD * DD;
    size_t wFD = (size_t)LL * FF * DD;
    unsigned char* kwb  = (unsigned char*)take(wDD);
    unsigned char* vwb  = (unsigned char*)take(wDD);
    unsigned char* rwb  = (unsigned char*)take(wDD);
    unsigned char* owb  = (unsigned char*)take(wDD);
    unsigned char* frwb = (unsigned char*)take(wDD);
    unsigned char* fkwb = (unsigned char*)take(wFD);
    unsigned char* fvwb = (unsigned char*)take(wFD);
    bool usef8 = (ws_size >= off);

    hipMemsetAsync(bar, 0, 16384, stream);

    SP P;
    P.tok = (const int*)d_in[0];
    P.emb = (const float*)d_in[1];
    P.pos = (const float*)d_in[2];
    P.l0w = (const float*)d_in[3];  P.l0b = (const float*)d_in[4];
    P.l1w = (const float*)d_in[5];  P.l1b = (const float*)d_in[6];
    P.l2w = (const float*)d_in[7];  P.l2b = (const float*)d_in[8];
    P.tmk = (const float*)d_in[9];  P.tmv = (const float*)d_in[10]; P.tmr = (const float*)d_in[11];
    P.tf  = (const float*)d_in[12]; P.tdr = (const float*)d_in[13];
    P.ftmk = (const float*)d_in[18]; P.ftmr = (const float*)d_in[19];
    P.low = (const float*)d_in[23]; P.lob = (const float*)d_in[24];
    P.xg = xg; P.xmid = xmid; P.rwkv = rwkv; P.fk = fk; P.td = td;
    P.aa = aa; P.bb = bb; P.pp = pp; P.sxa = sxa; P.sxf = sxf; P.v1 = v1; P.v2 = v2;
    P.XbT = XbT; P.bar = bar;

    if (usef8) {
        struct CV { const float* s; unsigned char* d; size_t n; } cv[7] = {
            {(const float*)d_in[14], kwb,  wDD}, {(const float*)d_in[15], vwb,  wDD},
            {(const float*)d_in[16], rwb,  wDD}, {(const float*)d_in[17], owb,  wDD},
            {(const float*)d_in[22], frwb, wDD},
            {(const float*)d_in[20], fkwb, wFD}, {(const float*)d_in[21], fvwb, wFD},
        };
        for (int i = 0; i < 7; ++i)
            cvt_fp8<<<dim3(2048), dim3(256), 0, stream>>>(cv[i].s, cv[i].d, (long)cv[i].n);
        P.kw = kwb; P.vw = vwb; P.rw = rwb; P.ow = owb; P.fkw = fkwb; P.fvw = fvwb; P.frw = frwb;
        spike_wave<true><<<dim3(NBLK), dim3(NTH), 0, stream>>>(P);
    } else {
        P.kw = d_in[14]; P.vw = d_in[15]; P.rw = d_in[16]; P.ow = d_in[17];
        P.fkw = d_in[20]; P.fvw = d_in[21]; P.frw = d_in[22];
        spike_wave<false><<<dim3(NBLK), dim3(NTH), 0, stream>>>(P);
    }
    int nwave = (VV + 7) / 8;
    int nblk  = (nwave + 3) / 4;
    head_simple<<<dim3(nblk), dim3(256), 0, stream>>>((const float*)d_in[25], XbT,
                                                      (float*)d_out);
}